// Round 5
// baseline (1104.189 us; speedup 1.0000x reference)
//
#include <hip/hip_runtime.h>
#include <hip/hip_bf16.h>
#include <cstdint>
#include <cstddef>

namespace {

constexpr int Hh = 512;
constexpr int G3 = 1536;   // 3*H
constexpr int Bb = 32;
constexpr int Tt = 64;
constexpr int Vv = 32000;

typedef __attribute__((ext_vector_type(8))) short short8;
typedef __attribute__((ext_vector_type(4))) float f32x4;

__device__ __forceinline__ unsigned bf16bits(float f) {
  union { __hip_bfloat16 h; unsigned short u; } c;
  c.h = __float2bfloat16(f);
  return (unsigned)c.u;
}

// async global->LDS, 16B per lane; LDS dest = wave-uniform base + lane*16
__device__ __forceinline__ void gl_lds16(const void* g, void* l) {
  __builtin_amdgcn_global_load_lds(
      (const __attribute__((address_space(1))) unsigned int*)g,
      (__attribute__((address_space(3))) unsigned int*)l, 16, 0, 0);
}

// ---------------- f32 -> bf16 convert (vectorized) ----------------
__global__ void cvt_bf16_k(const float* __restrict__ src, __hip_bfloat16* __restrict__ dst, int n4) {
  int i = blockIdx.x * blockDim.x + threadIdx.x;
  if (i >= n4) return;
  float4 v = ((const float4*)src)[i];
  union { __hip_bfloat16 h[4]; uint2 u; } o;
  o.h[0] = __float2bfloat16(v.x);
  o.h[1] = __float2bfloat16(v.y);
  o.h[2] = __float2bfloat16(v.z);
  o.h[3] = __float2bfloat16(v.w);
  ((uint2*)dst)[i] = o.u;
}

// ---------------- pack Whh[1536][512] -> P[k][i] = {bf16 r, bf16 z | bf16 n, 0} uint2, 2MB ----------------
__global__ void pack_whh_bf_k(const float* __restrict__ Whh, uint2* __restrict__ P) {
  __shared__ float tw[3][32][65];
  const int k0 = blockIdx.x * 64, i0 = blockIdx.y * 32;
  const int t = threadIdx.x;               // 256
  const int kk = t & 63, r4 = t >> 6;
  for (int ri = r4; ri < 96; ri += 4) {
    const int g = ri >> 5, ii = ri & 31;
    tw[g][ii][kk] = Whh[(size_t)(g * 512 + i0 + ii) * 512 + k0 + kk];
  }
  __syncthreads();
  const int ii = t & 31, kq = t >> 5;
  for (int k2 = kq; k2 < 64; k2 += 8) {
    unsigned rb = bf16bits(tw[0][ii][k2]);
    unsigned zb = bf16bits(tw[1][ii][k2]);
    unsigned nb = bf16bits(tw[2][ii][k2]);
    P[(size_t)(k0 + k2) * 512 + i0 + ii] = make_uint2((zb << 16) | rb, nb);
  }
}

// ---------------- embedding gather (optionally relu) -> bf16 [2048][512] ----------------
__global__ void embed_k(const int* __restrict__ idx, const float* __restrict__ emb,
                        __hip_bfloat16* __restrict__ outp, int do_relu) {
  int row = blockIdx.x;            // 0..2047 (= b*64+t)
  int r = idx[row];
  float4 v = ((const float4*)(emb + (size_t)r * Hh))[threadIdx.x];  // 128 thr * 4
  if (do_relu) {
    v.x = fmaxf(v.x, 0.f); v.y = fmaxf(v.y, 0.f);
    v.z = fmaxf(v.z, 0.f); v.w = fmaxf(v.w, 0.f);
  }
  union { __hip_bfloat16 h[4]; uint2 u; } o;
  o.h[0] = __float2bfloat16(v.x);
  o.h[1] = __float2bfloat16(v.y);
  o.h[2] = __float2bfloat16(v.z);
  o.h[3] = __float2bfloat16(v.w);
  ((uint2*)(outp + (size_t)row * Hh))[threadIdx.x] = o.u;
}

// ---------------- zero u32 ----------------
__global__ void zero_k(unsigned* __restrict__ p, int n) {
  int i = blockIdx.x * blockDim.x + threadIdx.x;
  if (i < n) p[i] = 0u;
}

// ---------------- relu(thought)->bf16, padded to 128 rows ----------------
__global__ void thought_prep_k(const float* __restrict__ th, __hip_bfloat16* __restrict__ outp) {
  int row = blockIdx.x;  // 0..127
  float4 v = {0.f, 0.f, 0.f, 0.f};
  if (row < Bb) v = ((const float4*)(th + (size_t)row * Hh))[threadIdx.x];
  v.x = fmaxf(v.x, 0.f); v.y = fmaxf(v.y, 0.f);
  v.z = fmaxf(v.z, 0.f); v.w = fmaxf(v.w, 0.f);
  union { __hip_bfloat16 h[4]; uint2 u; } o;
  o.h[0] = __float2bfloat16(v.x);
  o.h[1] = __float2bfloat16(v.y);
  o.h[2] = __float2bfloat16(v.z);
  o.h[3] = __float2bfloat16(v.w);
  ((uint2*)(outp + (size_t)row * Hh))[threadIdx.x] = o.u;
}

// ---------------- bf16 MFMA GEMM: C[M,N](f32) = A[M,K]*B[N,K]^T (+bias1[n]) (+bias2[(m>>6)*1536+n])
// 1D grid (XCD-chunked bijective swizzle, m-fastest for per-XCD B-panel L2 reuse).
// tile 128x128, BK=64, 4 waves; global_load_lds width-16 staging (m97 structure).
__global__ __launch_bounds__(256) void gemm_bf16_k(
    const __hip_bfloat16* __restrict__ A,
    const __hip_bfloat16* __restrict__ B,
    float* __restrict__ C,
    int lda, int ldb, int ldc, int K,
    const float* __restrict__ bias1,
    const float* __restrict__ bias2,
    int ntm) {
  __shared__ __align__(16) char smem[32768];
  auto sA = (__hip_bfloat16(*)[64])smem;            // [128][64]
  auto sB = (__hip_bfloat16(*)[64])(smem + 16384);  // [128][64]

  // bijective XCD-chunked swizzle (works for any nwg)
  const unsigned nwg = gridDim.x, gid = blockIdx.x;
  const unsigned q = nwg >> 3, r8 = nwg & 7, xc = gid & 7, jj = gid >> 3;
  const unsigned wg = (xc < r8 ? xc * (q + 1) : r8 * (q + 1) + (xc - r8) * q) + jj;
  const int m0 = (int)(wg % (unsigned)ntm) << 7;
  const int n0 = (int)(wg / (unsigned)ntm) << 7;

  const int tid = threadIdx.x;
  const int l = tid & 63, w = tid >> 6;
  const int wm = (w & 1) << 6, wn = (w >> 1) << 6;
  const int lr = l & 15;                 // fragment row within 16
  const int lk = (l >> 4) << 3;          // k-offset within 32
  const int lrow = (w << 3) + (l >> 3);  // staging row within 32-group (wave covers 8 rows)
  const int lcol = (l & 7) << 3;         // staging col (elems), 8 bf16 = 16B

  f32x4 acc[4][4];
  #pragma unroll
  for (int i = 0; i < 4; ++i) {
    #pragma unroll
    for (int j = 0; j < 4; ++j) acc[i][j] = {0.f, 0.f, 0.f, 0.f};
  }

  for (int k0 = 0; k0 < K; k0 += 64) {
    #pragma unroll
    for (int rr = 0; rr < 4; ++rr) {
      gl_lds16(A + (size_t)(m0 + (rr << 5) + lrow) * lda + k0 + lcol, &sA[(rr << 5) + (w << 3)][0]);
      gl_lds16(B + (size_t)(n0 + (rr << 5) + lrow) * ldb + k0 + lcol, &sB[(rr << 5) + (w << 3)][0]);
    }
    __syncthreads();   // compiler drains vmcnt(0) before barrier
    #pragma unroll
    for (int kk = 0; kk < 64; kk += 32) {
      short8 aF[4], bF[4];
      #pragma unroll
      for (int ms = 0; ms < 4; ++ms) aF[ms] = *(const short8*)(&sA[wm + (ms << 4) + lr][kk + lk]);
      #pragma unroll
      for (int ns = 0; ns < 4; ++ns) bF[ns] = *(const short8*)(&sB[wn + (ns << 4) + lr][kk + lk]);
      #pragma unroll
      for (int ms = 0; ms < 4; ++ms) {
        #pragma unroll
        for (int ns = 0; ns < 4; ++ns) {
          acc[ms][ns] = __builtin_amdgcn_mfma_f32_16x16x32_bf16(aF[ms], bF[ns], acc[ms][ns], 0, 0, 0);
        }
      }
    }
    __syncthreads();
  }

  // ---- epilogue: LDS round-trip per 16-row group, coalesced float4 stores ----
  float* sg = (float*)smem + w * 1088;      // 16 rows * 68 f32 per wave
  const int r2w = l >> 4;
  const int cw = l & 15;
  const int rbase = r2w << 2;
  #pragma unroll
  for (int ms = 0; ms < 4; ++ms) {
    #pragma unroll
    for (int ns = 0; ns < 4; ++ns) {
      #pragma unroll
      for (int r = 0; r < 4; ++r) sg[(rbase + r) * 68 + (ns << 4) + lr] = acc[ms][ns][r];
    }
    #pragma unroll
    for (int qq = 0; qq < 4; ++qq) {
      const int srow2 = (qq << 2) + r2w;
      float4 v = *(const float4*)&sg[srow2 * 68 + (cw << 2)];
      const int row = m0 + wm + (ms << 4) + srow2;
      const int col = n0 + wn + (cw << 2);
      if (bias1) {
        float4 b1 = *(const float4*)&bias1[col];
        v.x += b1.x; v.y += b1.y; v.z += b1.z; v.w += b1.w;
      }
      if (bias2) {
        float4 b2 = *(const float4*)&bias2[(size_t)(row >> 6) * G3 + col];
        v.x += b2.x; v.y += b2.y; v.z += b2.z; v.w += b2.w;
      }
      *(float4*)&C[(size_t)row * ldc + col] = v;
    }
  }
}

// ---------------- persistent GRU: all 64 steps in ONE launch ----------------
// grid (16 i-slices of 32, 8 batch-groups of 4) = 128 blocks x 512 thr (co-resident).
// Sync design (round-3 post-mortem fix): h exchanged through LLC via RELAXED
// agent-scope 4B atomics (sc1 path: no L2 pollution, no stale L2 reads).
// Per (step, bg) a write-once padded counter is fetch_add'ed by each of the 16
// blocks after __syncthreads (which drains vmcnt(0) -> h stores are at LLC);
// consumers poll it with RELAXED loads (no acquire -> NO buffer_inv -> Whh/xp
// stay L2-hot across all 64 steps). No fences, no cache maintenance at all.
__global__ __launch_bounds__(512, 1) void gru_seq2_k(
    const float* __restrict__ xp,        // [2048,1536], row m=b*64+t, includes bih(+tp)
    const uint2* __restrict__ whhB,      // [512k][512i] packed bf16
    const float* __restrict__ bhh,       // [1536]
    float* __restrict__ h0,              // [32,512] zeroed before launch
    float* __restrict__ h1,              // [32,512]
    __hip_bfloat16* __restrict__ dec_out,// null or [2048,512]
    unsigned* __restrict__ cnts) {       // [64 t][8 bg] stride-16 u32 (64B), zeroed
  const int tid = threadIdx.x;
  const int i0 = blockIdx.x << 5;
  const int bg = blockIdx.y;
  const int il = tid & 31, kc = tid >> 5;   // 32 i x 16 k-chunks(32k each)
  __shared__ __align__(16) float sH[4 * 512];
  __shared__ float sRed[512 * 13];
  const uint2* wp = whhB + i0 + il;
  const int kb0 = kc << 5;

  #pragma unroll 1
  for (int t = 0; t < Tt; ++t) {
    const float* hin = (t & 1) ? h1 : h0;
    float* hout = (t & 1) ? h0 : h1;

    // wait for step t-1 producers of this batch-group (t=0: h0 pre-zeroed)
    if (t > 0 && tid == 0) {
      const unsigned* c = cnts + (((t - 1) << 3) + bg) * 16;
      while (__hip_atomic_load(c, __ATOMIC_RELAXED, __HIP_MEMORY_SCOPE_AGENT) < 16u)
        __builtin_amdgcn_s_sleep(1);
    }
    __syncthreads();

    // load h (4 batches x 512) via LLC-path atomic loads
    {
      const unsigned* hb = (const unsigned*)(hin + ((size_t)bg << 11));
      #pragma unroll
      for (int j = 0; j < 4; ++j) {
        unsigned u = __hip_atomic_load(hb + tid + (j << 9), __ATOMIC_RELAXED, __HIP_MEMORY_SCOPE_AGENT);
        sH[tid + (j << 9)] = __uint_as_float(u);
      }
    }
    __syncthreads();

    float a[12];
    #pragma unroll
    for (int v = 0; v < 12; ++v) a[v] = 0.f;
    #pragma unroll 2
    for (int k4 = 0; k4 < 8; ++k4) {
      const int kb = kb0 + (k4 << 2);
      float4 hv0 = *(const float4*)&sH[kb];
      float4 hv1 = *(const float4*)&sH[512 + kb];
      float4 hv2 = *(const float4*)&sH[1024 + kb];
      float4 hv3 = *(const float4*)&sH[1536 + kb];
      const float* h0p = (const float*)&hv0;
      const float* h1p = (const float*)&hv1;
      const float* h2p = (const float*)&hv2;
      const float* h3p = (const float*)&hv3;
      #pragma unroll
      for (int j = 0; j < 4; ++j) {
        uint2 wv = wp[(size_t)(kb + j) << 9];
        const float wr = __uint_as_float(wv.x << 16);
        const float wz = __uint_as_float(wv.x & 0xffff0000u);
        const float wn = __uint_as_float(wv.y << 16);
        a[0]  = fmaf(wr, h0p[j], a[0]);  a[1]  = fmaf(wz, h0p[j], a[1]);  a[2]  = fmaf(wn, h0p[j], a[2]);
        a[3]  = fmaf(wr, h1p[j], a[3]);  a[4]  = fmaf(wz, h1p[j], a[4]);  a[5]  = fmaf(wn, h1p[j], a[5]);
        a[6]  = fmaf(wr, h2p[j], a[6]);  a[7]  = fmaf(wz, h2p[j], a[7]);  a[8]  = fmaf(wn, h2p[j], a[8]);
        a[9]  = fmaf(wr, h3p[j], a[9]);  a[10] = fmaf(wz, h3p[j], a[10]); a[11] = fmaf(wn, h3p[j], a[11]);
      }
    }
    {
      float* red = &sRed[tid * 13];
      #pragma unroll
      for (int v = 0; v < 12; ++v) red[v] = a[v];
    }
    __syncthreads();

    if (tid < 128) {
      const int b = tid >> 5, i2 = tid & 31;
      float s0 = 0.f, s1 = 0.f, s2 = 0.f;
      #pragma unroll
      for (int kc2 = 0; kc2 < 16; ++kc2) {
        const float* rp = &sRed[(kc2 * 32 + i2) * 13 + b * 3];
        s0 += rp[0]; s1 += rp[1]; s2 += rp[2];
      }
      const int gi = i0 + i2;
      const int bb = (bg << 2) + b;
      const int m = bb * Tt + t;
      const float hr = s0 + bhh[gi];
      const float hz = s1 + bhh[512 + gi];
      const float hn = s2 + bhh[1024 + gi];
      const float xr = xp[(size_t)m * G3 + gi];
      const float xz = xp[(size_t)m * G3 + 512 + gi];
      const float xn = xp[(size_t)m * G3 + 1024 + gi];
      const float rg = 1.f / (1.f + __expf(-(xr + hr)));
      const float zg = 1.f / (1.f + __expf(-(xz + hz)));
      const float ng = tanhf(xn + rg * hn);
      const float hnew = (1.f - zg) * ng + zg * sH[(b << 9) + gi];
      __hip_atomic_store((unsigned*)&hout[((size_t)bb << 9) + gi], __float_as_uint(hnew),
                         __ATOMIC_RELAXED, __HIP_MEMORY_SCOPE_AGENT);
      if (dec_out) dec_out[((size_t)m << 9) + gi] = __float2bfloat16(hnew);
    }
    __syncthreads();   // drains vmcnt(0): h stores are at LLC before the count

    if (tid == 0) {
      unsigned* c = cnts + ((t << 3) + bg) * 16;
      __hip_atomic_fetch_add(c, 1u, __ATOMIC_RELAXED, __HIP_MEMORY_SCOPE_AGENT);
    }
  }
}

// ---------------- in-place row log-softmax over V=32000 (one WG per row) ----------------
__global__ __launch_bounds__(256) void row_logsoftmax_k(float* __restrict__ X) {
  const int row = blockIdx.x;
  float4* p4 = (float4*)(X + (size_t)row * Vv);
  const int n4 = Vv / 4;  // 8000
  const int tid = threadIdx.x;
  float m = -3.4e38f, s = 0.f;
  for (int j = tid; j < n4; j += 256) {
    float4 v = p4[j];
    float xs[4] = {v.x, v.y, v.z, v.w};
    #pragma unroll
    for (int q = 0; q < 4; ++q) {
      float x = xs[q];
      if (x > m) { s = s * __expf(m - x) + 1.f; m = x; }
      else       { s += __expf(x - m); }
    }
  }
  #pragma unroll
  for (int off = 32; off > 0; off >>= 1) {
    float mo = __shfl_down(m, off);
    float so = __shfl_down(s, off);
    float M = fmaxf(m, mo);
    s = s * __expf(m - M) + so * __expf(mo - M);
    m = M;
  }
  __shared__ float sm[4], ss[4];
  if ((tid & 63) == 0) { sm[tid >> 6] = m; ss[tid >> 6] = s; }
  __syncthreads();
  const float M4 = fmaxf(fmaxf(sm[0], sm[1]), fmaxf(sm[2], sm[3]));
  const float S = ss[0] * __expf(sm[0] - M4) + ss[1] * __expf(sm[1] - M4) +
                  ss[2] * __expf(sm[2] - M4) + ss[3] * __expf(sm[3] - M4);
  const float c = M4 + __logf(S);
  for (int j = tid; j < n4; j += 256) {
    float4 v = p4[j];
    v.x -= c; v.y -= c; v.z -= c; v.w -= c;
    p4[j] = v;
  }
}

}  // namespace

extern "C" void kernel_launch(void* const* d_in, const int* in_sizes, int n_in,
                              void* d_out, int out_size, void* d_ws, size_t ws_size,
                              hipStream_t stream) {
  (void)in_sizes; (void)n_in; (void)out_size; (void)ws_size;
  const int*   in_seq  = (const int*)d_in[0];
  const int*   tgt_seq = (const int*)d_in[1];
  const float* enc_emb = (const float*)d_in[2];
  const float* enc_Wih = (const float*)d_in[3];
  const float* enc_Whh = (const float*)d_in[4];
  const float* enc_bih = (const float*)d_in[5];
  const float* enc_bhh = (const float*)d_in[6];
  const float* dec_emb = (const float*)d_in[7];
  const float* dec_Wih = (const float*)d_in[8];
  const float* dec_Whh = (const float*)d_in[9];
  const float* dec_bih = (const float*)d_in[10];
  const float* dec_bhh = (const float*)d_in[11];
  const float* out_W   = (const float*)d_in[12];
  const float* out_b   = (const float*)d_in[13];
  float* out = (float*)d_out;

  char* ws = (char*)d_ws;
  size_t off = 0;
  auto alloc = [&](size_t bytes) -> void* {
    void* p = (void*)(ws + off);
    off += (bytes + 255) & ~(size_t)255;
    return p;
  };
  uint2* whhB_e            = (uint2*)alloc((size_t)512 * 512 * 8);   // 2MB packed bf16
  uint2* whhB_d            = (uint2*)alloc((size_t)512 * 512 * 8);
  __hip_bfloat16* encWih_bf = (__hip_bfloat16*)alloc((size_t)1536 * 512 * 2);
  __hip_bfloat16* decWih_bf = (__hip_bfloat16*)alloc((size_t)1536 * 1024 * 2);
  __hip_bfloat16* outW_bf   = (__hip_bfloat16*)alloc((size_t)32000 * 512 * 2);
  __hip_bfloat16* encX_bf   = (__hip_bfloat16*)alloc((size_t)2048 * 512 * 2);
  __hip_bfloat16* decX_bf   = (__hip_bfloat16*)alloc((size_t)2048 * 512 * 2);
  float* enc_xp            = (float*)alloc((size_t)2048 * 1536 * 4);
  float* dec_xp            = (float*)alloc((size_t)2048 * 1536 * 4);
  float* tp                = (float*)alloc((size_t)128 * 1536 * 4);
  __hip_bfloat16* th_bf     = (__hip_bfloat16*)alloc((size_t)128 * 512 * 2);
  float* h0                = (float*)alloc((size_t)32 * 512 * 4);
  float* h1                = (float*)alloc((size_t)32 * 512 * 4);
  __hip_bfloat16* decOut_bf = (__hip_bfloat16*)alloc((size_t)2048 * 512 * 2);
  unsigned* cnts_e         = (unsigned*)alloc((size_t)64 * 8 * 16 * 4);  // 32KB padded counters
  unsigned* cnts_d         = (unsigned*)alloc((size_t)64 * 8 * 16 * 4);

  // --- weight preprocessing ---
  cvt_bf16_k<<<768, 256, 0, stream>>>(enc_Wih, encWih_bf, 1536 * 512 / 4);
  cvt_bf16_k<<<1536, 256, 0, stream>>>(dec_Wih, decWih_bf, 1536 * 1024 / 4);
  cvt_bf16_k<<<16000, 256, 0, stream>>>(out_W, outW_bf, 32000 * 512 / 4);
  pack_whh_bf_k<<<dim3(8, 16), 256, 0, stream>>>(enc_Whh, whhB_e);
  pack_whh_bf_k<<<dim3(8, 16), 256, 0, stream>>>(dec_Whh, whhB_d);

  // --- embeddings ---
  embed_k<<<2048, 128, 0, stream>>>(in_seq, enc_emb, encX_bf, 0);
  embed_k<<<2048, 128, 0, stream>>>(tgt_seq, dec_emb, decX_bf, 1);

  // --- zero counters (both GRUs) + h0 ---
  zero_k<<<64, 256, 0, stream>>>(cnts_e, 2 * 64 * 8 * 16);   // covers cnts_e and cnts_d (contiguous)
  zero_k<<<64, 256, 0, stream>>>((unsigned*)h0, Bb * Hh);

  // --- encoder xp = enc_x @ Wih^T + bih : [2048,1536] ---
  gemm_bf16_k<<<192, 256, 0, stream>>>(encX_bf, encWih_bf, enc_xp,
                                       512, 512, G3, 512, enc_bih, nullptr, 16);

  // --- encoder GRU: persistent, 1 launch ---
  gru_seq2_k<<<dim3(16, 8), 512, 0, stream>>>(enc_xp, whhB_e, enc_bhh, h0, h1, nullptr, cnts_e);
  // t=63 (odd) wrote h0 -> thought lives in h0

  // --- tp = relu(thought) @ dec_Wih[:,512:]^T + dec_bih : [128(pad),1536] ---
  thought_prep_k<<<128, 128, 0, stream>>>(h0, th_bf);
  gemm_bf16_k<<<12, 256, 0, stream>>>(th_bf, decWih_bf + 512, tp,
                                      512, 1024, G3, 512, dec_bih, nullptr, 1);

  // --- decoder xp = relu(dec_x) @ dec_Wih[:,:512]^T + tp[b] : [2048,1536] ---
  gemm_bf16_k<<<192, 256, 0, stream>>>(decX_bf, decWih_bf, dec_xp,
                                       512, 1024, G3, 512, nullptr, tp, 16);

  // --- decoder GRU: persistent, 1 launch ---
  zero_k<<<64, 256, 0, stream>>>((unsigned*)h0, Bb * Hh);
  gru_seq2_k<<<dim3(16, 8), 512, 0, stream>>>(dec_xp, whhB_d, dec_bhh, h0, h1, decOut_bf, cnts_d);

  // --- logits = dec_out @ out_W^T + out_b -> d_out (f32) ---
  gemm_bf16_k<<<4000, 256, 0, stream>>>(decOut_bf, outW_bf, out,
                                        512, 512, Vv, 512, out_b, nullptr, 16);

  // --- in-place log-softmax over V ---
  row_logsoftmax_k<<<2048, 256, 0, stream>>>(out);
}

// Round 7
// 1022.688 us; speedup vs baseline: 1.0797x; 1.0797x over previous
//
#include <hip/hip_runtime.h>
#include <hip/hip_bf16.h>
#include <cstdint>
#include <cstddef>

namespace {

constexpr int Hh = 512;
constexpr int G3 = 1536;   // 3*H
constexpr int Bb = 32;
constexpr int Tt = 64;
constexpr int Vv = 32000;

typedef __attribute__((ext_vector_type(8))) short short8;
typedef __attribute__((ext_vector_type(4))) float f32x4;
typedef unsigned long long ull;

__device__ __forceinline__ unsigned bf16bits(float f) {
  union { __hip_bfloat16 h; unsigned short u; } c;
  c.h = __float2bfloat16(f);
  return (unsigned)c.u;
}

// async global->LDS, 16B per lane; LDS dest = wave-uniform base + lane*16
__device__ __forceinline__ void gl_lds16(const void* g, void* l) {
  __builtin_amdgcn_global_load_lds(
      (const __attribute__((address_space(1))) unsigned int*)g,
      (__attribute__((address_space(3))) unsigned int*)l, 16, 0, 0);
}

// ---------------- f32 -> bf16 convert (vectorized) ----------------
__global__ void cvt_bf16_k(const float* __restrict__ src, __hip_bfloat16* __restrict__ dst, int n4) {
  int i = blockIdx.x * blockDim.x + threadIdx.x;
  if (i >= n4) return;
  float4 v = ((const float4*)src)[i];
  union { __hip_bfloat16 h[4]; uint2 u; } o;
  o.h[0] = __float2bfloat16(v.x);
  o.h[1] = __float2bfloat16(v.y);
  o.h[2] = __float2bfloat16(v.z);
  o.h[3] = __float2bfloat16(v.w);
  ((uint2*)dst)[i] = o.u;
}

// ---------------- pack Whh[1536][512] -> P[k][i] = {bf16 r, bf16 z | bf16 n, 0} uint2, 2MB ----------------
__global__ void pack_whh_bf_k(const float* __restrict__ Whh, uint2* __restrict__ P) {
  __shared__ float tw[3][32][65];
  const int k0 = blockIdx.x * 64, i0 = blockIdx.y * 32;
  const int t = threadIdx.x;               // 256
  const int kk = t & 63, r4 = t >> 6;
  for (int ri = r4; ri < 96; ri += 4) {
    const int g = ri >> 5, ii = ri & 31;
    tw[g][ii][kk] = Whh[(size_t)(g * 512 + i0 + ii) * 512 + k0 + kk];
  }
  __syncthreads();
  const int ii = t & 31, kq = t >> 5;
  for (int k2 = kq; k2 < 64; k2 += 8) {
    unsigned rb = bf16bits(tw[0][ii][k2]);
    unsigned zb = bf16bits(tw[1][ii][k2]);
    unsigned nb = bf16bits(tw[2][ii][k2]);
    P[(size_t)(k0 + k2) * 512 + i0 + ii] = make_uint2((zb << 16) | rb, nb);
  }
}

// ---------------- embedding gather (optionally relu) -> bf16 [2048][512] ----------------
__global__ void embed_k(const int* __restrict__ idx, const float* __restrict__ emb,
                        __hip_bfloat16* __restrict__ outp, int do_relu) {
  int row = blockIdx.x;            // 0..2047 (= b*64+t)
  int r = idx[row];
  float4 v = ((const float4*)(emb + (size_t)r * Hh))[threadIdx.x];  // 128 thr * 4
  if (do_relu) {
    v.x = fmaxf(v.x, 0.f); v.y = fmaxf(v.y, 0.f);
    v.z = fmaxf(v.z, 0.f); v.w = fmaxf(v.w, 0.f);
  }
  union { __hip_bfloat16 h[4]; uint2 u; } o;
  o.h[0] = __float2bfloat16(v.x);
  o.h[1] = __float2bfloat16(v.y);
  o.h[2] = __float2bfloat16(v.z);
  o.h[3] = __float2bfloat16(v.w);
  ((uint2*)(outp + (size_t)row * Hh))[threadIdx.x] = o.u;
}

// ---------------- zero u32 ----------------
__global__ void zero_k(unsigned* __restrict__ p, int n) {
  int i = blockIdx.x * blockDim.x + threadIdx.x;
  if (i < n) p[i] = 0u;
}

// ---------------- relu(thought)->bf16, padded to 128 rows ----------------
__global__ void thought_prep_k(const float* __restrict__ th, __hip_bfloat16* __restrict__ outp) {
  int row = blockIdx.x;  // 0..127
  float4 v = {0.f, 0.f, 0.f, 0.f};
  if (row < Bb) v = ((const float4*)(th + (size_t)row * Hh))[threadIdx.x];
  v.x = fmaxf(v.x, 0.f); v.y = fmaxf(v.y, 0.f);
  v.z = fmaxf(v.z, 0.f); v.w = fmaxf(v.w, 0.f);
  union { __hip_bfloat16 h[4]; uint2 u; } o;
  o.h[0] = __float2bfloat16(v.x);
  o.h[1] = __float2bfloat16(v.y);
  o.h[2] = __float2bfloat16(v.z);
  o.h[3] = __float2bfloat16(v.w);
  ((uint2*)(outp + (size_t)row * Hh))[threadIdx.x] = o.u;
}

// ---------------- bf16 MFMA GEMM: C[M,N](f32) = A[M,K]*B[N,K]^T (+bias1[n]) (+bias2[(m>>6)*1536+n])
// 1D grid (XCD-chunked bijective swizzle). tile 128x128, BK=64, 4 waves;
// global_load_lds width-16 staging (m97 structure).
// If partials != nullptr: also emit per-(row, 64-col half-tile) {rowmax, sum exp(v-rowmax)}
// to partials[row*500 + (n0>>6)+(wn>>6)] -- each slot has exactly ONE writer (race-free).
__global__ __launch_bounds__(256) void gemm_bf16_k(
    const __hip_bfloat16* __restrict__ A,
    const __hip_bfloat16* __restrict__ B,
    float* __restrict__ C,
    int lda, int ldb, int ldc, int K,
    const float* __restrict__ bias1,
    const float* __restrict__ bias2,
    float2* __restrict__ partials,
    int ntm) {
  __shared__ __align__(16) char smem[32768];
  auto sA = (__hip_bfloat16(*)[64])smem;            // [128][64]
  auto sB = (__hip_bfloat16(*)[64])(smem + 16384);  // [128][64]

  // bijective XCD-chunked swizzle (works for any nwg)
  const unsigned nwg = gridDim.x, gid = blockIdx.x;
  const unsigned q = nwg >> 3, r8 = nwg & 7, xc = gid & 7, jj = gid >> 3;
  const unsigned wg = (xc < r8 ? xc * (q + 1) : r8 * (q + 1) + (xc - r8) * q) + jj;
  const int m0 = (int)(wg % (unsigned)ntm) << 7;
  const int n0 = (int)(wg / (unsigned)ntm) << 7;

  const int tid = threadIdx.x;
  const int l = tid & 63, w = tid >> 6;
  const int wm = (w & 1) << 6, wn = (w >> 1) << 6;
  const int lr = l & 15;                 // fragment row within 16
  const int lk = (l >> 4) << 3;          // k-offset within 32
  const int lrow = (w << 3) + (l >> 3);  // staging row within 32-group
  const int lcol = (l & 7) << 3;         // staging col (elems), 8 bf16 = 16B

  f32x4 acc[4][4];
  #pragma unroll
  for (int i = 0; i < 4; ++i) {
    #pragma unroll
    for (int j = 0; j < 4; ++j) acc[i][j] = {0.f, 0.f, 0.f, 0.f};
  }

  for (int k0 = 0; k0 < K; k0 += 64) {
    #pragma unroll
    for (int rr = 0; rr < 4; ++rr) {
      gl_lds16(A + (size_t)(m0 + (rr << 5) + lrow) * lda + k0 + lcol, &sA[(rr << 5) + (w << 3)][0]);
      gl_lds16(B + (size_t)(n0 + (rr << 5) + lrow) * ldb + k0 + lcol, &sB[(rr << 5) + (w << 3)][0]);
    }
    __syncthreads();
    #pragma unroll
    for (int kk = 0; kk < 64; kk += 32) {
      short8 aF[4], bF[4];
      #pragma unroll
      for (int ms = 0; ms < 4; ++ms) aF[ms] = *(const short8*)(&sA[wm + (ms << 4) + lr][kk + lk]);
      #pragma unroll
      for (int ns = 0; ns < 4; ++ns) bF[ns] = *(const short8*)(&sB[wn + (ns << 4) + lr][kk + lk]);
      #pragma unroll
      for (int ms = 0; ms < 4; ++ms) {
        #pragma unroll
        for (int ns = 0; ns < 4; ++ns) {
          acc[ms][ns] = __builtin_amdgcn_mfma_f32_16x16x32_bf16(aF[ms], bF[ns], acc[ms][ns], 0, 0, 0);
        }
      }
    }
    __syncthreads();
  }

  // ---- epilogue: LDS round-trip per 16-row group, coalesced float4 stores ----
  float* sg = (float*)smem + w * 1088;      // 16 rows * 68 f32 per wave
  const int r2w = l >> 4;
  const int cw = l & 15;
  const int rbase = r2w << 2;
  #pragma unroll
  for (int ms = 0; ms < 4; ++ms) {
    #pragma unroll
    for (int ns = 0; ns < 4; ++ns) {
      #pragma unroll
      for (int r = 0; r < 4; ++r) sg[(rbase + r) * 68 + (ns << 4) + lr] = acc[ms][ns][r];
    }
    #pragma unroll
    for (int qq = 0; qq < 4; ++qq) {
      const int srow2 = (qq << 2) + r2w;
      float4 v = *(const float4*)&sg[srow2 * 68 + (cw << 2)];
      const int row = m0 + wm + (ms << 4) + srow2;
      const int col = n0 + wn + (cw << 2);
      if (bias1) {
        float4 b1 = *(const float4*)&bias1[col];
        v.x += b1.x; v.y += b1.y; v.z += b1.z; v.w += b1.w;
      }
      if (bias2) {
        float4 b2 = *(const float4*)&bias2[(size_t)(row >> 6) * G3 + col];
        v.x += b2.x; v.y += b2.y; v.z += b2.z; v.w += b2.w;
      }
      if (partials) {
        // row-segment softmax stats over this wave's 64 cols (16 lanes x 4)
        float m4 = fmaxf(fmaxf(v.x, v.y), fmaxf(v.z, v.w));
        #pragma unroll
        for (int hop = 1; hop < 16; hop <<= 1) m4 = fmaxf(m4, __shfl_xor(m4, hop));
        float e = __expf(v.x - m4) + __expf(v.y - m4) + __expf(v.z - m4) + __expf(v.w - m4);
        #pragma unroll
        for (int hop = 1; hop < 16; hop <<= 1) e += __shfl_xor(e, hop);
        if (cw == 0) partials[(size_t)row * 500 + ((n0 >> 6) + (wn >> 6))] = make_float2(m4, e);
      }
      *(float4*)&C[(size_t)row * ldc + col] = v;
    }
  }
}

// ---------------- persistent GRU v4: round-5 PROVEN sync skeleton + reg weights + flag array ----------------
// grid (16 i-slices of 32, 8 batch-groups of 4) = 128 blocks x 512 thr (co-resident).
// Ordering (deadlock-free, validated in round 5): every block unconditionally sets
// flags[t][bg][slice] at END of iteration t (after __syncthreads drains its UC h-stores);
// the poll for flags[t] happens at the START of the h(t+1) consumption — i.e. strictly
// after all peers' flag-set points in program order. No poll-hiding (round-6 lesson:
// polling an event produced after the poller's own phase deadlocks).
// h exchanged via RELAXED agent-scope atomics (LLC path, no L2 pollution/invalidates).
// Weights: step-invariant per-thread slice pre-decoded into 96 f32 VGPRs (no per-step
// weight traffic at all).
__global__ __launch_bounds__(512, 1) void gru_seq4_k(
    const float* __restrict__ xp,        // [2048,1536], row m=b*64+t, includes bih(+tp)
    const uint2* __restrict__ whhB,      // [512k][512i] packed bf16
    const float* __restrict__ bhh,       // [1536]
    float* __restrict__ h0,              // [32,512] zeroed before launch
    float* __restrict__ h1,              // [32,512]
    __hip_bfloat16* __restrict__ dec_out,// null or [2048,512]
    unsigned* __restrict__ flags) {      // [64 t][8 bg][16] u32, zeroed
  const int tid = threadIdx.x;
  const int slice = blockIdx.x;             // 0..15
  const int i0 = slice << 5;
  const int bg = blockIdx.y;
  const int il = tid & 31, kc = tid >> 5;   // 32 i x 16 k-chunks(32k each)
  __shared__ __align__(16) float sH[4 * 512];
  __shared__ float sRed[512 * 13];
  const int kb0 = kc << 5;

  // ---- prologue: load + decode step-invariant weights into registers ----
  float wrF[32], wzF[32], wnF[32];
  {
    const uint2* wp = whhB + i0 + il;
    #pragma unroll
    for (int k4 = 0; k4 < 8; ++k4) {
      #pragma unroll
      for (int j = 0; j < 4; ++j) {
        uint2 wv = wp[(size_t)(kb0 + (k4 << 2) + j) << 9];
        const int idx = (k4 << 2) + j;
        wrF[idx] = __uint_as_float(wv.x << 16);
        wzF[idx] = __uint_as_float(wv.x & 0xffff0000u);
        wnF[idx] = __uint_as_float(wv.y << 16);
      }
    }
  }

  // ---- prologue: h(0) -> sH ----
  {
    const ull* hb = (const ull*)(h0 + ((size_t)bg << 11));
    ull u0 = __hip_atomic_load(hb + tid, __ATOMIC_RELAXED, __HIP_MEMORY_SCOPE_AGENT);
    ull u1 = __hip_atomic_load(hb + tid + 512, __ATOMIC_RELAXED, __HIP_MEMORY_SCOPE_AGENT);
    ((ull*)sH)[tid] = u0;
    ((ull*)sH)[tid + 512] = u1;
  }
  __syncthreads();

  #pragma unroll 1
  for (int t = 0; t < Tt; ++t) {
    float* hout = (t & 1) ? h0 : h1;

    float a[12];
    #pragma unroll
    for (int v = 0; v < 12; ++v) a[v] = 0.f;
    #pragma unroll
    for (int k4 = 0; k4 < 8; ++k4) {
      const int kb = kb0 + (k4 << 2);
      float4 hv0 = *(const float4*)&sH[kb];
      float4 hv1 = *(const float4*)&sH[512 + kb];
      float4 hv2 = *(const float4*)&sH[1024 + kb];
      float4 hv3 = *(const float4*)&sH[1536 + kb];
      const float* h0p = (const float*)&hv0;
      const float* h1p = (const float*)&hv1;
      const float* h2p = (const float*)&hv2;
      const float* h3p = (const float*)&hv3;
      #pragma unroll
      for (int j = 0; j < 4; ++j) {
        const int idx = (k4 << 2) + j;
        const float wr = wrF[idx], wz = wzF[idx], wn = wnF[idx];
        a[0]  = fmaf(wr, h0p[j], a[0]);  a[1]  = fmaf(wz, h0p[j], a[1]);  a[2]  = fmaf(wn, h0p[j], a[2]);
        a[3]  = fmaf(wr, h1p[j], a[3]);  a[4]  = fmaf(wz, h1p[j], a[4]);  a[5]  = fmaf(wn, h1p[j], a[5]);
        a[6]  = fmaf(wr, h2p[j], a[6]);  a[7]  = fmaf(wz, h2p[j], a[7]);  a[8]  = fmaf(wn, h2p[j], a[8]);
        a[9]  = fmaf(wr, h3p[j], a[9]);  a[10] = fmaf(wz, h3p[j], a[10]); a[11] = fmaf(wn, h3p[j], a[11]);
      }
    }
    {
      float* red = &sRed[tid * 13];
      #pragma unroll
      for (int v = 0; v < 12; ++v) red[v] = a[v];
    }
    __syncthreads();   // B1: sRed complete

    if (tid < 128) {
      const int b = tid >> 5, i2 = tid & 31;
      float s0 = 0.f, s1 = 0.f, s2 = 0.f;
      #pragma unroll
      for (int kc2 = 0; kc2 < 16; ++kc2) {
        const float* rp = &sRed[(kc2 * 32 + i2) * 13 + b * 3];
        s0 += rp[0]; s1 += rp[1]; s2 += rp[2];
      }
      const int gi = i0 + i2;
      const int bb = (bg << 2) + b;
      const int m = bb * Tt + t;
      const float hr = s0 + bhh[gi];
      const float hz = s1 + bhh[512 + gi];
      const float hn = s2 + bhh[1024 + gi];
      const float xr = xp[(size_t)m * G3 + gi];
      const float xz = xp[(size_t)m * G3 + 512 + gi];
      const float xn = xp[(size_t)m * G3 + 1024 + gi];
      const float rg = 1.f / (1.f + __expf(-(xr + hr)));
      const float zg = 1.f / (1.f + __expf(-(xz + hz)));
      const float ng = tanhf(xn + rg * hn);
      const float hnew = (1.f - zg) * ng + zg * sH[(b << 9) + gi];
      __hip_atomic_store((unsigned*)&hout[((size_t)bb << 9) + gi], __float_as_uint(hnew),
                         __ATOMIC_RELAXED, __HIP_MEMORY_SCOPE_AGENT);
      if (dec_out) dec_out[((size_t)m << 9) + gi] = __float2bfloat16(hnew);
    }
    __syncthreads();   // B2: drains h stores (vmcnt 0) before flag

    if (tid == 0) {
      __hip_atomic_store(flags + (((unsigned)t << 3) + bg) * 16 + slice, 1u,
                         __ATOMIC_RELAXED, __HIP_MEMORY_SCOPE_AGENT);
    }

    if (t < Tt - 1) {
      // poll peers' flags for THIS step (all set before their polls; own excluded)
      if (tid < 64) {
        const unsigned* fl = flags + (((unsigned)t << 3) + bg) * 16;
        const bool need = (tid < 16) && (tid != slice);
        while (true) {
          unsigned v = need ? __hip_atomic_load(fl + tid, __ATOMIC_RELAXED, __HIP_MEMORY_SCOPE_AGENT) : 1u;
          if (__all(v != 0)) break;
          __builtin_amdgcn_s_sleep(1);
        }
      }
      __syncthreads();   // B3: poll complete for all waves
      const ull* hb = (const ull*)(hout + ((size_t)bg << 11));
      ull u0 = __hip_atomic_load(hb + tid, __ATOMIC_RELAXED, __HIP_MEMORY_SCOPE_AGENT);
      ull u1 = __hip_atomic_load(hb + tid + 512, __ATOMIC_RELAXED, __HIP_MEMORY_SCOPE_AGENT);
      ((ull*)sH)[tid] = u0;
      ((ull*)sH)[tid + 512] = u1;
      __syncthreads();   // B4: sH ready for next step
    }
  }
}

// ---------------- final log-softmax: reduce per-row partials, subtract in place ----------------
__global__ __launch_bounds__(256) void lsm_final_k(float* __restrict__ X,
                                                   const float2* __restrict__ P) {
  const int row = blockIdx.x;
  const int tid = threadIdx.x;
  float m = -3.4e38f, s = 0.f;
  for (int j = tid; j < 500; j += 256) {
    float2 p = P[(size_t)row * 500 + j];
    if (p.x > m) { s = s * __expf(m - p.x) + p.y; m = p.x; }
    else         { s += p.y * __expf(p.x - m); }
  }
  #pragma unroll
  for (int off2 = 32; off2 > 0; off2 >>= 1) {
    float mo = __shfl_down(m, off2);
    float so = __shfl_down(s, off2);
    float M = fmaxf(m, mo);
    s = s * __expf(m - M) + so * __expf(mo - M);
    m = M;
  }
  __shared__ float sm[4], ss[4];
  if ((tid & 63) == 0) { sm[tid >> 6] = m; ss[tid >> 6] = s; }
  __syncthreads();
  const float M4 = fmaxf(fmaxf(sm[0], sm[1]), fmaxf(sm[2], sm[3]));
  const float S = ss[0] * __expf(sm[0] - M4) + ss[1] * __expf(sm[1] - M4) +
                  ss[2] * __expf(sm[2] - M4) + ss[3] * __expf(sm[3] - M4);
  const float c = M4 + __logf(S);
  float4* p4 = (float4*)(X + (size_t)row * Vv);
  for (int j = tid; j < Vv / 4; j += 256) {
    float4 v = p4[j];
    v.x -= c; v.y -= c; v.z -= c; v.w -= c;
    p4[j] = v;
  }
}

}  // namespace

extern "C" void kernel_launch(void* const* d_in, const int* in_sizes, int n_in,
                              void* d_out, int out_size, void* d_ws, size_t ws_size,
                              hipStream_t stream) {
  (void)in_sizes; (void)n_in; (void)out_size; (void)ws_size;
  const int*   in_seq  = (const int*)d_in[0];
  const int*   tgt_seq = (const int*)d_in[1];
  const float* enc_emb = (const float*)d_in[2];
  const float* enc_Wih = (const float*)d_in[3];
  const float* enc_Whh = (const float*)d_in[4];
  const float* enc_bih = (const float*)d_in[5];
  const float* enc_bhh = (const float*)d_in[6];
  const float* dec_emb = (const float*)d_in[7];
  const float* dec_Wih = (const float*)d_in[8];
  const float* dec_Whh = (const float*)d_in[9];
  const float* dec_bih = (const float*)d_in[10];
  const float* dec_bhh = (const float*)d_in[11];
  const float* out_W   = (const float*)d_in[12];
  const float* out_b   = (const float*)d_in[13];
  float* out = (float*)d_out;

  char* ws = (char*)d_ws;
  size_t off = 0;
  auto alloc = [&](size_t bytes) -> void* {
    void* p = (void*)(ws + off);
    off += (bytes + 255) & ~(size_t)255;
    return p;
  };
  uint2* whhB_e            = (uint2*)alloc((size_t)512 * 512 * 8);   // 2MB packed bf16
  uint2* whhB_d            = (uint2*)alloc((size_t)512 * 512 * 8);
  __hip_bfloat16* encWih_bf = (__hip_bfloat16*)alloc((size_t)1536 * 512 * 2);
  __hip_bfloat16* decWih_bf = (__hip_bfloat16*)alloc((size_t)1536 * 1024 * 2);
  __hip_bfloat16* outW_bf   = (__hip_bfloat16*)alloc((size_t)32000 * 512 * 2);
  __hip_bfloat16* encX_bf   = (__hip_bfloat16*)alloc((size_t)2048 * 512 * 2);
  __hip_bfloat16* decX_bf   = (__hip_bfloat16*)alloc((size_t)2048 * 512 * 2);
  float* enc_xp            = (float*)alloc((size_t)2048 * 1536 * 4);
  float* dec_xp            = (float*)alloc((size_t)2048 * 1536 * 4);
  float* tp                = (float*)alloc((size_t)128 * 1536 * 4);
  __hip_bfloat16* th_bf     = (__hip_bfloat16*)alloc((size_t)128 * 512 * 2);
  float* h0                = (float*)alloc((size_t)32 * 512 * 4);
  float* h1                = (float*)alloc((size_t)32 * 512 * 4);
  __hip_bfloat16* decOut_bf = (__hip_bfloat16*)alloc((size_t)2048 * 512 * 2);
  unsigned* flags_e        = (unsigned*)alloc((size_t)64 * 8 * 16 * 4);  // write-once flags
  unsigned* flags_d        = (unsigned*)alloc((size_t)64 * 8 * 16 * 4);
  float2* partials         = (float2*)alloc((size_t)2048 * 500 * 8);    // 8.2MB softmax stats

  // --- weight preprocessing ---
  cvt_bf16_k<<<768, 256, 0, stream>>>(enc_Wih, encWih_bf, 1536 * 512 / 4);
  cvt_bf16_k<<<1536, 256, 0, stream>>>(dec_Wih, decWih_bf, 1536 * 1024 / 4);
  cvt_bf16_k<<<16000, 256, 0, stream>>>(out_W, outW_bf, 32000 * 512 / 4);
  pack_whh_bf_k<<<dim3(8, 16), 256, 0, stream>>>(enc_Whh, whhB_e);
  pack_whh_bf_k<<<dim3(8, 16), 256, 0, stream>>>(dec_Whh, whhB_d);

  // --- embeddings ---
  embed_k<<<2048, 128, 0, stream>>>(in_seq, enc_emb, encX_bf, 0);
  embed_k<<<2048, 128, 0, stream>>>(tgt_seq, dec_emb, decX_bf, 1);

  // --- zero flags (both GRUs, contiguous) + h0 ---
  zero_k<<<64, 256, 0, stream>>>(flags_e, 2 * 64 * 8 * 16);
  zero_k<<<64, 256, 0, stream>>>((unsigned*)h0, Bb * Hh);

  // --- encoder xp = enc_x @ Wih^T + bih : [2048,1536] ---
  gemm_bf16_k<<<192, 256, 0, stream>>>(encX_bf, encWih_bf, enc_xp,
                                       512, 512, G3, 512, enc_bih, nullptr, nullptr, 16);

  // --- encoder GRU: persistent, 1 launch ---
  gru_seq4_k<<<dim3(16, 8), 512, 0, stream>>>(enc_xp, whhB_e, enc_bhh, h0, h1, nullptr, flags_e);
  // t=63 (odd) wrote h0 -> thought lives in h0

  // --- tp = relu(thought) @ dec_Wih[:,512:]^T + dec_bih : [128(pad),1536] ---
  thought_prep_k<<<128, 128, 0, stream>>>(h0, th_bf);
  gemm_bf16_k<<<12, 256, 0, stream>>>(th_bf, decWih_bf + 512, tp,
                                      512, 1024, G3, 512, dec_bih, nullptr, nullptr, 1);

  // --- decoder xp = relu(dec_x) @ dec_Wih[:,:512]^T + tp[b] : [2048,1536] ---
  gemm_bf16_k<<<192, 256, 0, stream>>>(decX_bf, decWih_bf, dec_xp,
                                       512, 1024, G3, 512, nullptr, tp, nullptr, 16);

  // --- decoder GRU: persistent, 1 launch ---
  zero_k<<<64, 256, 0, stream>>>((unsigned*)h0, Bb * Hh);
  gru_seq4_k<<<dim3(16, 8), 512, 0, stream>>>(dec_xp, whhB_d, dec_bhh, h0, h1, decOut_bf, flags_d);

  // --- logits = dec_out @ out_W^T + out_b -> d_out (f32) + fused softmax stats ---
  gemm_bf16_k<<<4000, 256, 0, stream>>>(decOut_bf, outW_bf, out,
                                        512, 512, Vv, 512, out_b, nullptr, partials, 16);

  // --- final: reduce partials + subtract logZ in place ---
  lsm_final_k<<<2048, 256, 0, stream>>>(out, partials);
}

// Round 8
// 978.394 us; speedup vs baseline: 1.1286x; 1.0453x over previous
//
#include <hip/hip_runtime.h>
#include <hip/hip_bf16.h>
#include <cstdint>
#include <cstddef>

namespace {

constexpr int Hh = 512;
constexpr int G3 = 1536;   // 3*H
constexpr int Bb = 32;
constexpr int Tt = 64;
constexpr int Vv = 32000;

typedef __attribute__((ext_vector_type(8))) short short8;
typedef __attribute__((ext_vector_type(4))) float f32x4;
typedef unsigned long long ull;

__device__ __forceinline__ unsigned bf16bits(float f) {
  union { __hip_bfloat16 h; unsigned short u; } c;
  c.h = __float2bfloat16(f);
  return (unsigned)c.u;
}

// async global->LDS, 16B per lane; LDS dest = wave-uniform base + lane*16
__device__ __forceinline__ void gl_lds16(const void* g, void* l) {
  __builtin_amdgcn_global_load_lds(
      (const __attribute__((address_space(1))) unsigned int*)g,
      (__attribute__((address_space(3))) unsigned int*)l, 16, 0, 0);
}

// ---------------- f32 -> bf16 convert (vectorized) ----------------
__global__ void cvt_bf16_k(const float* __restrict__ src, __hip_bfloat16* __restrict__ dst, int n4) {
  int i = blockIdx.x * blockDim.x + threadIdx.x;
  if (i >= n4) return;
  float4 v = ((const float4*)src)[i];
  union { __hip_bfloat16 h[4]; uint2 u; } o;
  o.h[0] = __float2bfloat16(v.x);
  o.h[1] = __float2bfloat16(v.y);
  o.h[2] = __float2bfloat16(v.z);
  o.h[3] = __float2bfloat16(v.w);
  ((uint2*)dst)[i] = o.u;
}

// ---------------- pack Whh[1536][512] -> P[k][i] = {bf16 r, bf16 z | bf16 n, 0} uint2, 2MB ----------------
__global__ void pack_whh_bf_k(const float* __restrict__ Whh, uint2* __restrict__ P) {
  __shared__ float tw[3][32][65];
  const int k0 = blockIdx.x * 64, i0 = blockIdx.y * 32;
  const int t = threadIdx.x;               // 256
  const int kk = t & 63, r4 = t >> 6;
  for (int ri = r4; ri < 96; ri += 4) {
    const int g = ri >> 5, ii = ri & 31;
    tw[g][ii][kk] = Whh[(size_t)(g * 512 + i0 + ii) * 512 + k0 + kk];
  }
  __syncthreads();
  const int ii = t & 31, kq = t >> 5;
  for (int k2 = kq; k2 < 64; k2 += 8) {
    unsigned rb = bf16bits(tw[0][ii][k2]);
    unsigned zb = bf16bits(tw[1][ii][k2]);
    unsigned nb = bf16bits(tw[2][ii][k2]);
    P[(size_t)(k0 + k2) * 512 + i0 + ii] = make_uint2((zb << 16) | rb, nb);
  }
}

// ---------------- embedding gather (optionally relu) -> bf16 [2048][512] ----------------
__global__ void embed_k(const int* __restrict__ idx, const float* __restrict__ emb,
                        __hip_bfloat16* __restrict__ outp, int do_relu) {
  int row = blockIdx.x;            // 0..2047 (= b*64+t)
  int r = idx[row];
  float4 v = ((const float4*)(emb + (size_t)r * Hh))[threadIdx.x];  // 128 thr * 4
  if (do_relu) {
    v.x = fmaxf(v.x, 0.f); v.y = fmaxf(v.y, 0.f);
    v.z = fmaxf(v.z, 0.f); v.w = fmaxf(v.w, 0.f);
  }
  union { __hip_bfloat16 h[4]; uint2 u; } o;
  o.h[0] = __float2bfloat16(v.x);
  o.h[1] = __float2bfloat16(v.y);
  o.h[2] = __float2bfloat16(v.z);
  o.h[3] = __float2bfloat16(v.w);
  ((uint2*)(outp + (size_t)row * Hh))[threadIdx.x] = o.u;
}

// ---------------- zero u32 ----------------
__global__ void zero_k(unsigned* __restrict__ p, int n) {
  int i = blockIdx.x * blockDim.x + threadIdx.x;
  if (i < n) p[i] = 0u;
}

// ---------------- relu(thought)->bf16 from tagged-h buffer, padded to 128 rows ----------------
__global__ void thought_prep2_k(const ull* __restrict__ th, __hip_bfloat16* __restrict__ outp) {
  int row = blockIdx.x;  // 0..127 ; 128 threads, 4 elems each
  const int c = threadIdx.x << 2;
  float4 v = {0.f, 0.f, 0.f, 0.f};
  if (row < Bb) {
    const ull* p = th + (size_t)row * Hh + c;
    v.x = __uint_as_float((unsigned)p[0]);
    v.y = __uint_as_float((unsigned)p[1]);
    v.z = __uint_as_float((unsigned)p[2]);
    v.w = __uint_as_float((unsigned)p[3]);
  }
  v.x = fmaxf(v.x, 0.f); v.y = fmaxf(v.y, 0.f);
  v.z = fmaxf(v.z, 0.f); v.w = fmaxf(v.w, 0.f);
  union { __hip_bfloat16 h[4]; uint2 u; } o;
  o.h[0] = __float2bfloat16(v.x);
  o.h[1] = __float2bfloat16(v.y);
  o.h[2] = __float2bfloat16(v.z);
  o.h[3] = __float2bfloat16(v.w);
  ((uint2*)(outp + (size_t)row * Hh))[threadIdx.x] = o.u;
}

// ---------------- bf16 MFMA GEMM: C[M,N](f32) = A[M,K]*B[N,K]^T (+bias1[n]) (+bias2[(m>>6)*1536+n])
// 1D grid (XCD-chunked bijective swizzle). tile 128x128, BK=64, 4 waves;
// global_load_lds width-16 staging (m97 structure).
// If partials != nullptr: also emit per-(row, 64-col half-tile) {rowmax, sum exp(v-rowmax)}
// to partials[row*500 + (n0>>6)+(wn>>6)] -- each slot has exactly ONE writer (race-free).
__global__ __launch_bounds__(256) void gemm_bf16_k(
    const __hip_bfloat16* __restrict__ A,
    const __hip_bfloat16* __restrict__ B,
    float* __restrict__ C,
    int lda, int ldb, int ldc, int K,
    const float* __restrict__ bias1,
    const float* __restrict__ bias2,
    float2* __restrict__ partials,
    int ntm) {
  __shared__ __align__(16) char smem[32768];
  auto sA = (__hip_bfloat16(*)[64])smem;            // [128][64]
  auto sB = (__hip_bfloat16(*)[64])(smem + 16384);  // [128][64]

  // bijective XCD-chunked swizzle (works for any nwg)
  const unsigned nwg = gridDim.x, gid = blockIdx.x;
  const unsigned q = nwg >> 3, r8 = nwg & 7, xc = gid & 7, jj = gid >> 3;
  const unsigned wg = (xc < r8 ? xc * (q + 1) : r8 * (q + 1) + (xc - r8) * q) + jj;
  const int m0 = (int)(wg % (unsigned)ntm) << 7;
  const int n0 = (int)(wg / (unsigned)ntm) << 7;

  const int tid = threadIdx.x;
  const int l = tid & 63, w = tid >> 6;
  const int wm = (w & 1) << 6, wn = (w >> 1) << 6;
  const int lr = l & 15;                 // fragment row within 16
  const int lk = (l >> 4) << 3;          // k-offset within 32
  const int lrow = (w << 3) + (l >> 3);  // staging row within 32-group
  const int lcol = (l & 7) << 3;         // staging col (elems), 8 bf16 = 16B

  f32x4 acc[4][4];
  #pragma unroll
  for (int i = 0; i < 4; ++i) {
    #pragma unroll
    for (int j = 0; j < 4; ++j) acc[i][j] = {0.f, 0.f, 0.f, 0.f};
  }

  for (int k0 = 0; k0 < K; k0 += 64) {
    #pragma unroll
    for (int rr = 0; rr < 4; ++rr) {
      gl_lds16(A + (size_t)(m0 + (rr << 5) + lrow) * lda + k0 + lcol, &sA[(rr << 5) + (w << 3)][0]);
      gl_lds16(B + (size_t)(n0 + (rr << 5) + lrow) * ldb + k0 + lcol, &sB[(rr << 5) + (w << 3)][0]);
    }
    __syncthreads();
    #pragma unroll
    for (int kk = 0; kk < 64; kk += 32) {
      short8 aF[4], bF[4];
      #pragma unroll
      for (int ms = 0; ms < 4; ++ms) aF[ms] = *(const short8*)(&sA[wm + (ms << 4) + lr][kk + lk]);
      #pragma unroll
      for (int ns = 0; ns < 4; ++ns) bF[ns] = *(const short8*)(&sB[wn + (ns << 4) + lr][kk + lk]);
      #pragma unroll
      for (int ms = 0; ms < 4; ++ms) {
        #pragma unroll
        for (int ns = 0; ns < 4; ++ns) {
          acc[ms][ns] = __builtin_amdgcn_mfma_f32_16x16x32_bf16(aF[ms], bF[ns], acc[ms][ns], 0, 0, 0);
        }
      }
    }
    __syncthreads();
  }

  // ---- epilogue: LDS round-trip per 16-row group, coalesced float4 stores ----
  float* sg = (float*)smem + w * 1088;      // 16 rows * 68 f32 per wave
  const int r2w = l >> 4;
  const int cw = l & 15;
  const int rbase = r2w << 2;
  #pragma unroll
  for (int ms = 0; ms < 4; ++ms) {
    #pragma unroll
    for (int ns = 0; ns < 4; ++ns) {
      #pragma unroll
      for (int r = 0; r < 4; ++r) sg[(rbase + r) * 68 + (ns << 4) + lr] = acc[ms][ns][r];
    }
    #pragma unroll
    for (int qq = 0; qq < 4; ++qq) {
      const int srow2 = (qq << 2) + r2w;
      float4 v = *(const float4*)&sg[srow2 * 68 + (cw << 2)];
      const int row = m0 + wm + (ms << 4) + srow2;
      const int col = n0 + wn + (cw << 2);
      if (bias1) {
        float4 b1 = *(const float4*)&bias1[col];
        v.x += b1.x; v.y += b1.y; v.z += b1.z; v.w += b1.w;
      }
      if (bias2) {
        float4 b2 = *(const float4*)&bias2[(size_t)(row >> 6) * G3 + col];
        v.x += b2.x; v.y += b2.y; v.z += b2.z; v.w += b2.w;
      }
      if (partials) {
        float m4 = fmaxf(fmaxf(v.x, v.y), fmaxf(v.z, v.w));
        #pragma unroll
        for (int hop = 1; hop < 16; hop <<= 1) m4 = fmaxf(m4, __shfl_xor(m4, hop));
        float e = __expf(v.x - m4) + __expf(v.y - m4) + __expf(v.z - m4) + __expf(v.w - m4);
        #pragma unroll
        for (int hop = 1; hop < 16; hop <<= 1) e += __shfl_xor(e, hop);
        if (cw == 0) partials[(size_t)row * 500 + ((n0 >> 6) + (wn >> 6))] = make_float2(m4, e);
      }
      *(float4*)&C[(size_t)row * ldc + col] = v;
    }
  }
}

// ---------------- persistent GRU v5: tagged-value h exchange (1 LLC hop per step) ----------------
// grid (16 i-slices of 32, 8 batch-groups of 4) = 128 blocks x 512 thr (co-resident).
// h element = 8B word {tag=step<<32 | f32 bits}, stored with ONE relaxed agent-scope
// atomic -- the store IS the signal, the consumer's poll IS the data load.
// hTag[2][32][512]: buffer = step parity. Zeroed buffer == valid h(0) with tag 0.
// Progress: poll at iter t waits for tag==t written unconditionally at END of every
// peer's iter t-1 (strictly-before the peer's own iter-t poll -> no circular wait;
// round-6 deadlock class structurally excluded). WAR-safe: a block writes tag t+2
// only after observing all t+1 tags, which peers emit only after reading all of t.
__global__ __launch_bounds__(512, 1) void gru_seq5_k(
    const float* __restrict__ xp,        // [2048,1536], row m=b*64+t, includes bih(+tp)
    const uint2* __restrict__ whhB,      // [512k][512i] packed bf16
    const float* __restrict__ bhh,       // [1536]
    ull* __restrict__ hTag,              // [2][32][512] tagged h, zeroed before launch
    __hip_bfloat16* __restrict__ dec_out)// null or [2048,512]
{
  const int tid = threadIdx.x;
  const int slice = blockIdx.x;             // 0..15
  const int i0 = slice << 5;
  const int bg = blockIdx.y;
  const int il = tid & 31, kc = tid >> 5;   // 32 i x 16 k-chunks(32k each)
  __shared__ __align__(16) float sH[4 * 512];
  __shared__ float sRed[512 * 13];
  const int kb0 = kc << 5;

  // ---- prologue: load + decode step-invariant weights into 96 VGPRs ----
  float wrF[32], wzF[32], wnF[32];
  {
    const uint2* wp = whhB + i0 + il;
    #pragma unroll
    for (int k4 = 0; k4 < 8; ++k4) {
      #pragma unroll
      for (int j = 0; j < 4; ++j) {
        uint2 wv = wp[(size_t)(kb0 + (k4 << 2) + j) << 9];
        const int idx = (k4 << 2) + j;
        wrF[idx] = __uint_as_float(wv.x << 16);
        wzF[idx] = __uint_as_float(wv.x & 0xffff0000u);
        wnF[idx] = __uint_as_float(wv.y << 16);
      }
    }
  }

  #pragma unroll 1
  for (int t = 0; t < Tt; ++t) {
    // ---- poll+load h(t): tag must equal t (buffer = t parity) ----
    {
      const ull* hb = hTag + ((size_t)(t & 1) << 14) + ((size_t)bg << 11);
      #pragma unroll
      for (int j = 0; j < 4; ++j) {
        const ull* p = hb + (j << 9) + tid;
        ull v = __hip_atomic_load(p, __ATOMIC_RELAXED, __HIP_MEMORY_SCOPE_AGENT);
        while ((unsigned)(v >> 32) != (unsigned)t) {
          __builtin_amdgcn_s_sleep(1);
          v = __hip_atomic_load(p, __ATOMIC_RELAXED, __HIP_MEMORY_SCOPE_AGENT);
        }
        sH[(j << 9) + tid] = __uint_as_float((unsigned)v);
      }
    }
    __syncthreads();   // B0: sH(t) complete

    float a[12];
    #pragma unroll
    for (int v = 0; v < 12; ++v) a[v] = 0.f;
    #pragma unroll
    for (int k4 = 0; k4 < 8; ++k4) {
      const int kb = kb0 + (k4 << 2);
      float4 hv0 = *(const float4*)&sH[kb];
      float4 hv1 = *(const float4*)&sH[512 + kb];
      float4 hv2 = *(const float4*)&sH[1024 + kb];
      float4 hv3 = *(const float4*)&sH[1536 + kb];
      const float* h0p = (const float*)&hv0;
      const float* h1p = (const float*)&hv1;
      const float* h2p = (const float*)&hv2;
      const float* h3p = (const float*)&hv3;
      #pragma unroll
      for (int j = 0; j < 4; ++j) {
        const int idx = (k4 << 2) + j;
        const float wr = wrF[idx], wz = wzF[idx], wn = wnF[idx];
        a[0]  = fmaf(wr, h0p[j], a[0]);  a[1]  = fmaf(wz, h0p[j], a[1]);  a[2]  = fmaf(wn, h0p[j], a[2]);
        a[3]  = fmaf(wr, h1p[j], a[3]);  a[4]  = fmaf(wz, h1p[j], a[4]);  a[5]  = fmaf(wn, h1p[j], a[5]);
        a[6]  = fmaf(wr, h2p[j], a[6]);  a[7]  = fmaf(wz, h2p[j], a[7]);  a[8]  = fmaf(wn, h2p[j], a[8]);
        a[9]  = fmaf(wr, h3p[j], a[9]);  a[10] = fmaf(wz, h3p[j], a[10]); a[11] = fmaf(wn, h3p[j], a[11]);
      }
    }
    {
      float* red = &sRed[tid * 13];
      #pragma unroll
      for (int v = 0; v < 12; ++v) red[v] = a[v];
    }
    __syncthreads();   // B1: sRed complete

    if (tid < 128) {
      const int b = tid >> 5, i2 = tid & 31;
      float s0 = 0.f, s1 = 0.f, s2 = 0.f;
      #pragma unroll
      for (int kc2 = 0; kc2 < 16; ++kc2) {
        const float* rp = &sRed[(kc2 * 32 + i2) * 13 + b * 3];
        s0 += rp[0]; s1 += rp[1]; s2 += rp[2];
      }
      const int gi = i0 + i2;
      const int bb = (bg << 2) + b;
      const int m = bb * Tt + t;
      const float hr = s0 + bhh[gi];
      const float hz = s1 + bhh[512 + gi];
      const float hn = s2 + bhh[1024 + gi];
      const float xr = xp[(size_t)m * G3 + gi];
      const float xz = xp[(size_t)m * G3 + 512 + gi];
      const float xn = xp[(size_t)m * G3 + 1024 + gi];
      const float rg = 1.f / (1.f + __expf(-(xr + hr)));
      const float zg = 1.f / (1.f + __expf(-(xz + hz)));
      const float ng = tanhf(xn + rg * hn);
      const float hnew = (1.f - zg) * ng + zg * sH[(b << 9) + gi];
      // single 8B store carries value + readiness tag (t+1)
      ull* dst = hTag + ((size_t)((t + 1) & 1) << 14) + ((size_t)bb << 9) + gi;
      __hip_atomic_store(dst, ((ull)(unsigned)(t + 1) << 32) | (ull)__float_as_uint(hnew),
                         __ATOMIC_RELAXED, __HIP_MEMORY_SCOPE_AGENT);
      if (dec_out) dec_out[((size_t)m << 9) + gi] = __float2bfloat16(hnew);
    }
    __syncthreads();   // B2: protect sH/sRed against next iteration's writes
  }
}

// ---------------- final log-softmax: reduce per-row partials, subtract in place ----------------
__global__ __launch_bounds__(256) void lsm_final_k(float* __restrict__ X,
                                                   const float2* __restrict__ P) {
  const int row = blockIdx.x;
  const int tid = threadIdx.x;
  float m = -3.4e38f, s = 0.f;
  for (int j = tid; j < 500; j += 256) {
    float2 p = P[(size_t)row * 500 + j];
    if (p.x > m) { s = s * __expf(m - p.x) + p.y; m = p.x; }
    else         { s += p.y * __expf(p.x - m); }
  }
  #pragma unroll
  for (int off2 = 32; off2 > 0; off2 >>= 1) {
    float mo = __shfl_down(m, off2);
    float so = __shfl_down(s, off2);
    float M = fmaxf(m, mo);
    s = s * __expf(m - M) + so * __expf(mo - M);
    m = M;
  }
  __shared__ float sm[4], ss[4];
  if ((tid & 63) == 0) { sm[tid >> 6] = m; ss[tid >> 6] = s; }
  __syncthreads();
  const float M4 = fmaxf(fmaxf(sm[0], sm[1]), fmaxf(sm[2], sm[3]));
  const float S = ss[0] * __expf(sm[0] - M4) + ss[1] * __expf(sm[1] - M4) +
                  ss[2] * __expf(sm[2] - M4) + ss[3] * __expf(sm[3] - M4);
  const float c = M4 + __logf(S);
  float4* p4 = (float4*)(X + (size_t)row * Vv);
  for (int j = tid; j < Vv / 4; j += 256) {
    float4 v = p4[j];
    v.x -= c; v.y -= c; v.z -= c; v.w -= c;
    p4[j] = v;
  }
}

}  // namespace

extern "C" void kernel_launch(void* const* d_in, const int* in_sizes, int n_in,
                              void* d_out, int out_size, void* d_ws, size_t ws_size,
                              hipStream_t stream) {
  (void)in_sizes; (void)n_in; (void)out_size; (void)ws_size;
  const int*   in_seq  = (const int*)d_in[0];
  const int*   tgt_seq = (const int*)d_in[1];
  const float* enc_emb = (const float*)d_in[2];
  const float* enc_Wih = (const float*)d_in[3];
  const float* enc_Whh = (const float*)d_in[4];
  const float* enc_bih = (const float*)d_in[5];
  const float* enc_bhh = (const float*)d_in[6];
  const float* dec_emb = (const float*)d_in[7];
  const float* dec_Wih = (const float*)d_in[8];
  const float* dec_Whh = (const float*)d_in[9];
  const float* dec_bih = (const float*)d_in[10];
  const float* dec_bhh = (const float*)d_in[11];
  const float* out_W   = (const float*)d_in[12];
  const float* out_b   = (const float*)d_in[13];
  float* out = (float*)d_out;

  char* ws = (char*)d_ws;
  size_t off = 0;
  auto alloc = [&](size_t bytes) -> void* {
    void* p = (void*)(ws + off);
    off += (bytes + 255) & ~(size_t)255;
    return p;
  };
  uint2* whhB_e            = (uint2*)alloc((size_t)512 * 512 * 8);   // 2MB packed bf16
  uint2* whhB_d            = (uint2*)alloc((size_t)512 * 512 * 8);
  __hip_bfloat16* encWih_bf = (__hip_bfloat16*)alloc((size_t)1536 * 512 * 2);
  __hip_bfloat16* decWih_bf = (__hip_bfloat16*)alloc((size_t)1536 * 1024 * 2);
  __hip_bfloat16* outW_bf   = (__hip_bfloat16*)alloc((size_t)32000 * 512 * 2);
  __hip_bfloat16* encX_bf   = (__hip_bfloat16*)alloc((size_t)2048 * 512 * 2);
  __hip_bfloat16* decX_bf   = (__hip_bfloat16*)alloc((size_t)2048 * 512 * 2);
  float* enc_xp            = (float*)alloc((size_t)2048 * 1536 * 4);
  float* dec_xp            = (float*)alloc((size_t)2048 * 1536 * 4);
  float* tp                = (float*)alloc((size_t)128 * 1536 * 4);
  __hip_bfloat16* th_bf     = (__hip_bfloat16*)alloc((size_t)128 * 512 * 2);
  ull* hTag                = (ull*)alloc((size_t)2 * 32 * 512 * 8);  // 256KB tagged h
  __hip_bfloat16* decOut_bf = (__hip_bfloat16*)alloc((size_t)2048 * 512 * 2);
  float2* partials         = (float2*)alloc((size_t)2048 * 500 * 8); // 8.2MB softmax stats

  // --- weight preprocessing ---
  cvt_bf16_k<<<768, 256, 0, stream>>>(enc_Wih, encWih_bf, 1536 * 512 / 4);
  cvt_bf16_k<<<1536, 256, 0, stream>>>(dec_Wih, decWih_bf, 1536 * 1024 / 4);
  cvt_bf16_k<<<16000, 256, 0, stream>>>(out_W, outW_bf, 32000 * 512 / 4);
  pack_whh_bf_k<<<dim3(8, 16), 256, 0, stream>>>(enc_Whh, whhB_e);
  pack_whh_bf_k<<<dim3(8, 16), 256, 0, stream>>>(dec_Whh, whhB_d);

  // --- embeddings ---
  embed_k<<<2048, 128, 0, stream>>>(in_seq, enc_emb, encX_bf, 0);
  embed_k<<<2048, 128, 0, stream>>>(tgt_seq, dec_emb, decX_bf, 1);

  // --- encoder xp = enc_x @ Wih^T + bih : [2048,1536] ---
  gemm_bf16_k<<<192, 256, 0, stream>>>(encX_bf, encWih_bf, enc_xp,
                                       512, 512, G3, 512, enc_bih, nullptr, nullptr, 16);

  // --- encoder GRU: persistent, 1 launch (hTag zeroed => valid h(0)=0 tag 0) ---
  zero_k<<<128, 256, 0, stream>>>((unsigned*)hTag, 2 * 32 * 512 * 2);
  gru_seq5_k<<<dim3(16, 8), 512, 0, stream>>>(enc_xp, whhB_e, enc_bhh, hTag, nullptr);
  // h(64) tag 64 lives in buffer 0 (even parity)

  // --- tp = relu(thought) @ dec_Wih[:,512:]^T + dec_bih : [128(pad),1536] ---
  thought_prep2_k<<<128, 128, 0, stream>>>(hTag, th_bf);
  gemm_bf16_k<<<12, 256, 0, stream>>>(th_bf, decWih_bf + 512, tp,
                                      512, 1024, G3, 512, dec_bih, nullptr, nullptr, 1);

  // --- decoder xp = relu(dec_x) @ dec_Wih[:,:512]^T + tp[b] : [2048,1536] ---
  gemm_bf16_k<<<192, 256, 0, stream>>>(decX_bf, decWih_bf, dec_xp,
                                       512, 1024, G3, 512, nullptr, tp, nullptr, 16);

  // --- decoder GRU: persistent, 1 launch (re-zero tags!) ---
  zero_k<<<128, 256, 0, stream>>>((unsigned*)hTag, 2 * 32 * 512 * 2);
  gru_seq5_k<<<dim3(16, 8), 512, 0, stream>>>(dec_xp, whhB_d, dec_bhh, hTag, decOut_bf);

  // --- logits = dec_out @ out_W^T + out_b -> d_out (f32) + fused softmax stats ---
  gemm_bf16_k<<<4000, 256, 0, stream>>>(decOut_bf, outW_bf, out,
                                        512, 512, Vv, 512, out_b, nullptr, partials, 16);

  // --- final: reduce partials + subtract logZ in place ---
  lsm_final_k<<<2048, 256, 0, stream>>>(out, partials);
}